// Round 1
// baseline (37881.134 us; speedup 1.0000x reference)
//
#include <hip/hip_runtime.h>
#include <hip/hip_bf16.h>
#include <stdint.h>

typedef unsigned short ushort_t;

#define H   512
#define E   128
#define NC  27
#define NE  28
#define B   256
#define T   512
#define FH  2048  // 4*H

typedef __bf16 bf16x8 __attribute__((ext_vector_type(8)));
typedef float  f32x4  __attribute__((ext_vector_type(4)));

__device__ __forceinline__ ushort_t f2b(float x) {
    uint32_t u = __float_as_uint(x);
    uint32_t r = (u + 0x7FFFu + ((u >> 16) & 1u)) >> 16;
    return (ushort_t)r;
}
__device__ __forceinline__ float sigm(float x) {
    return 1.f / (1.f + __expf(-x));
}

// ---------------- setup kernels ----------------

__global__ void k_convert(const float* __restrict__ Whh, const float* __restrict__ Wih1,
                          ushort_t* __restrict__ WhhB, ushort_t* __restrict__ Wih1B) {
    const int n = 4 * FH * H;          // Whh elements (== Wih1 elements)
    for (int i = blockIdx.x * blockDim.x + threadIdx.x; i < n; i += gridDim.x * blockDim.x) {
        WhhB[i]  = f2b(Whh[i]);
        Wih1B[i] = f2b(Wih1[i]);
    }
}

// G0[d][e][n] = sum_k embed[e,k]*Wih0[d,n,k] + bih[0,d,n] + bhh[0,d,n]
// bias1[d*FH+n] = bih[1,d,n] + bhh[1,d,n]
__global__ void k_g0(const float* __restrict__ embed, const float* __restrict__ Wih0,
                     const float* __restrict__ bih, const float* __restrict__ bhh,
                     float* __restrict__ G0, float* __restrict__ bias1) {
    int i = blockIdx.x * blockDim.x + threadIdx.x;
    if (i < 2 * NE * FH) {
        int d = i / (NE * FH);
        int rem = i % (NE * FH);
        int e = rem / FH;
        int n = rem % FH;
        const float* er = embed + (size_t)e * E;
        const float* wr = Wih0 + ((size_t)d * FH + n) * E;
        float s = 0.f;
        #pragma unroll 8
        for (int k = 0; k < E; ++k) s += er[k] * wr[k];
        G0[i] = s + bih[(size_t)d * FH + n] + bhh[(size_t)d * FH + n];
    }
    if (i < 2 * FH) bias1[i] = bih[2 * FH + i] + bhh[2 * FH + i];
}

__global__ void k_state(const float* __restrict__ h0, const float* __restrict__ c0,
                        float* __restrict__ cst, ushort_t* __restrict__ hb16) {
    int i = blockIdx.x * blockDim.x + threadIdx.x;
    if (i >= 4 * B * H) return;
    cst[i] = c0[i];
    int cell = i / (B * H);
    int rem  = i % (B * H);
    hb16[((size_t)(cell * 2 + 1)) * (B * H) + rem] = f2b(h0[i]);   // parity 1 = "step -1"
}

__global__ void k_len(const int* __restrict__ lens, float* __restrict__ out_len) {
    int i = threadIdx.x;
    if (i < B) out_len[i] = (float)lens[i];
}

// ---------------- phase kernel ----------------
// Phase p (0..T+1):
//   blocks [0,64):    layer0 step t=p        (if p < T)
//   blocks [64,128):  layer1 step s=p-1      (if 1 <= p <= T)
//   blocks [128,144): logits step t2=p-2     (if 2 <= p <= T+1)
// hb16 layout: [cell][parity][B][H] bf16; parity(step) = step&1.
__global__ __launch_bounds__(512, 2) void k_phase(
    const ushort_t* __restrict__ WhhB, const ushort_t* __restrict__ Wih1B,
    const float* __restrict__ G0, const float* __restrict__ bias1,
    float* __restrict__ cst, ushort_t* __restrict__ hb16,
    const int* __restrict__ tok, const int* __restrict__ lens,
    const float* __restrict__ Wout, const float* __restrict__ bout,
    float* __restrict__ out, int p)
{
    const int bid = blockIdx.x;
    const int tid = threadIdx.x;

    if (bid < 64) {
        // ---------------- layer 0, cells 0/1 ----------------
        if (p >= T) return;
        const int cell = bid >> 5;
        const int jt   = bid & 31;
        const int lane = tid & 63, wave = tid >> 6;
        const int lrow = lane & 15, kg = lane >> 4;
        const int row0 = wave * 32;
        const int j0   = jt * 16;
        const int parR = (p + 1) & 1, parW = p & 1;

        const ushort_t* A = hb16 + (size_t)(cell * 2 + parR) * (B * H);
        const ushort_t* W = WhhB + (size_t)cell * FH * H;

        f32x4 acc[2][4];
        #pragma unroll
        for (int m = 0; m < 2; ++m)
            #pragma unroll
            for (int g = 0; g < 4; ++g) acc[m][g] = (f32x4){0.f, 0.f, 0.f, 0.f};

        const ushort_t* ar0 = A + (size_t)(row0 + lrow) * H + kg * 8;
        const ushort_t* wr0 = W + (size_t)(j0 + lrow) * H + kg * 8;   // gate 0 row; gates stride 512*H

        for (int k = 0; k < H; k += 32) {
            bf16x8 a0 = *(const bf16x8*)(ar0 + k);
            bf16x8 a1 = *(const bf16x8*)(ar0 + (size_t)16 * H + k);
            #pragma unroll
            for (int g = 0; g < 4; ++g) {
                bf16x8 bb = *(const bf16x8*)(wr0 + (size_t)g * 512 * H + k);
                acc[0][g] = __builtin_amdgcn_mfma_f32_16x16x32_bf16(a0, bb, acc[0][g], 0, 0, 0);
                acc[1][g] = __builtin_amdgcn_mfma_f32_16x16x32_bf16(a1, bb, acc[1][g], 0, 0, 0);
            }
        }

        const int j = j0 + lrow;
        #pragma unroll
        for (int mf = 0; mf < 2; ++mf) {
            #pragma unroll
            for (int r = 0; r < 4; ++r) {
                int bb = row0 + mf * 16 + kg * 4 + r;
                int tk = tok[(size_t)bb * T + p];
                const float* g0 = G0 + ((size_t)cell * NE + tk) * FH + j;
                float gi = acc[mf][0][r] + g0[0];
                float gf = acc[mf][1][r] + g0[512];
                float gg = acc[mf][2][r] + g0[1024];
                float go = acc[mf][3][r] + g0[1536];
                float ii = sigm(gi), ff = sigm(gf), oo = sigm(go);
                float tg = tanhf(gg);
                size_t ci = ((size_t)cell * B + bb) * H + j;
                float cn = ff * cst[ci] + ii * tg;
                cst[ci] = cn;
                float hn = oo * tanhf(cn);
                hb16[((size_t)(cell * 2 + parW) * B + bb) * H + j] = f2b(hn);
            }
        }
    } else if (bid < 128) {
        // ---------------- layer 1, cells 2/3 ----------------
        if (p < 1 || p > T) return;
        const int cell = 2 + ((bid - 64) >> 5);
        const int jt   = (bid - 64) & 31;
        const int lane = tid & 63, wave = tid >> 6;
        const int lrow = lane & 15, kg = lane >> 4;
        const int row0 = wave * 32;
        const int j0   = jt * 16;
        const int parY  = (p + 1) & 1;  // y0 parity = (p-1)&1
        const int parR2 = p & 1;        // own h at step p-2
        const int parW  = (p + 1) & 1;  // write step p-1

        const ushort_t* A0 = hb16 + (size_t)(0 * 2 + parY) * (B * H);
        const ushort_t* A1 = hb16 + (size_t)(1 * 2 + parY) * (B * H);
        const ushort_t* A2 = hb16 + (size_t)(cell * 2 + parR2) * (B * H);
        const ushort_t* Wi = Wih1B + (size_t)(cell - 2) * FH * (2 * H);
        const ushort_t* Wh = WhhB + (size_t)cell * FH * H;

        f32x4 acc[2][4];
        #pragma unroll
        for (int m = 0; m < 2; ++m)
            #pragma unroll
            for (int g = 0; g < 4; ++g) acc[m][g] = (f32x4){0.f, 0.f, 0.f, 0.f};

        // chunk helper: 512 K-steps over source A (row len H) vs weight Wmat (row len wld, col offset koff)
        auto chunk = [&](const ushort_t* A, const ushort_t* Wmat, size_t wld, int koff) {
            const ushort_t* ar0 = A + (size_t)(row0 + lrow) * H + kg * 8;
            const ushort_t* wr0 = Wmat + (size_t)(j0 + lrow) * wld + koff + kg * 8;
            for (int k = 0; k < H; k += 32) {
                bf16x8 a0 = *(const bf16x8*)(ar0 + k);
                bf16x8 a1 = *(const bf16x8*)(ar0 + (size_t)16 * H + k);
                #pragma unroll
                for (int g = 0; g < 4; ++g) {
                    bf16x8 bb = *(const bf16x8*)(wr0 + (size_t)g * 512 * wld + k);
                    acc[0][g] = __builtin_amdgcn_mfma_f32_16x16x32_bf16(a0, bb, acc[0][g], 0, 0, 0);
                    acc[1][g] = __builtin_amdgcn_mfma_f32_16x16x32_bf16(a1, bb, acc[1][g], 0, 0, 0);
                }
            }
        };
        chunk(A0, Wi, 2 * H, 0);    // y0 first half  (layer0 fwd h)
        chunk(A1, Wi, 2 * H, 512);  // y0 second half (layer0 bwd h)
        chunk(A2, Wh, H, 0);        // recurrent h

        const int j = j0 + lrow;
        const float* b1 = bias1 + (size_t)(cell - 2) * FH + j;
        #pragma unroll
        for (int mf = 0; mf < 2; ++mf) {
            #pragma unroll
            for (int r = 0; r < 4; ++r) {
                int bb = row0 + mf * 16 + kg * 4 + r;
                float gi = acc[mf][0][r] + b1[0];
                float gf = acc[mf][1][r] + b1[512];
                float gg = acc[mf][2][r] + b1[1024];
                float go = acc[mf][3][r] + b1[1536];
                float ii = sigm(gi), ff = sigm(gf), oo = sigm(go);
                float tg = tanhf(gg);
                size_t ci = ((size_t)cell * B + bb) * H + j;
                float cn = ff * cst[ci] + ii * tg;
                cst[ci] = cn;
                float hn = oo * tanhf(cn);
                hb16[((size_t)(cell * 2 + parW) * B + bb) * H + j] = f2b(hn);
            }
        }
    } else {
        // ---------------- logits, step t2 = p-2 ----------------
        if (p < 2 || p > T + 1) return;
        const int t2 = p - 2;
        const int parL = p & 1;        // = t2 & 1
        const int blk = bid - 128;
        const int bl = tid >> 5;
        const int c  = tid & 31;
        const int b  = blk * 16 + bl;
        if (c >= NC) return;

        const ushort_t* y2f = hb16 + (size_t)(2 * 2 + parL) * (B * H) + (size_t)b * H;
        const ushort_t* y2b = hb16 + (size_t)(3 * 2 + parL) * (B * H) + (size_t)b * H;
        const float* wr = Wout + (size_t)c * (2 * H);

        float s = 0.f;
        for (int k = 0; k < H; k += 8) {
            bf16x8 v = *(const bf16x8*)(y2f + k);
            #pragma unroll
            for (int i = 0; i < 8; ++i) s += (float)v[i] * wr[k + i];
        }
        for (int k = 0; k < H; k += 8) {
            bf16x8 v = *(const bf16x8*)(y2b + k);
            #pragma unroll
            for (int i = 0; i < 8; ++i) s += (float)v[i] * wr[512 + k + i];
        }
        float val = s + bout[c];
        out[((size_t)b * T + t2) * NC + c] = (t2 < lens[b]) ? val : 0.f;
    }
}

// ---------------- launch ----------------

extern "C" void kernel_launch(void* const* d_in, const int* in_sizes, int n_in,
                              void* d_out, int out_size, void* d_ws, size_t ws_size,
                              hipStream_t stream) {
    const int*   tok   = (const int*)d_in[0];
    const int*   lens  = (const int*)d_in[1];
    const float* h0    = (const float*)d_in[2];
    const float* c0    = (const float*)d_in[3];
    const float* embed = (const float*)d_in[4];
    const float* Wih0  = (const float*)d_in[5];
    const float* Wih1  = (const float*)d_in[6];
    const float* Whh   = (const float*)d_in[7];
    const float* bih   = (const float*)d_in[8];
    const float* bhh   = (const float*)d_in[9];
    const float* Wout  = (const float*)d_in[10];
    const float* bout  = (const float*)d_in[11];
    float* out = (float*)d_out;

    // workspace layout (bf16 region then f32 region), ~20.5 MB total
    ushort_t* WhhB  = (ushort_t*)d_ws;                       // [4][2048][512]
    ushort_t* Wih1B = WhhB + (size_t)4 * FH * H;             // [2][2048][1024]
    ushort_t* hb16  = Wih1B + (size_t)2 * FH * 2 * H;        // [4][2][256][512]
    float*    fbase = (float*)(hb16 + (size_t)4 * 2 * B * H);
    float*    G0    = fbase;                                 // [2][28][2048]
    float*    bias1 = G0 + 2 * NE * FH;                      // [2][2048]
    float*    cst   = bias1 + 2 * FH;                        // [4][256][512]

    k_convert<<<1024, 256, 0, stream>>>(Whh, Wih1, WhhB, Wih1B);
    k_g0<<<(2 * NE * FH + 255) / 256, 256, 0, stream>>>(embed, Wih0, bih, bhh, G0, bias1);
    k_state<<<(4 * B * H + 255) / 256, 256, 0, stream>>>(h0, c0, cst, hb16);
    k_len<<<1, 256, 0, stream>>>(lens, out + (size_t)B * T * NC);

    for (int p = 0; p <= T + 1; ++p) {
        k_phase<<<144, 512, 0, stream>>>(WhhB, Wih1B, G0, bias1, cst, hb16,
                                         tok, lens, Wout, bout, out, p);
    }
}

// Round 2
// 31284.836 us; speedup vs baseline: 1.2108x; 1.2108x over previous
//
#include <hip/hip_runtime.h>
#include <hip/hip_bf16.h>
#include <stdint.h>

typedef unsigned short ushort_t;

#define H   512
#define E   128
#define NC  27
#define NE  28
#define B   256
#define T   512
#define FH  2048        // 4*H
#define NPH (T + 2)     // phases 0..T+1
#define NBLK 224        // 64 L0 + 128 L1 + 32 OUT
#define LDS_BYTES (96 * 1024)

typedef __bf16 bf16x8 __attribute__((ext_vector_type(8)));
typedef float  f32x4  __attribute__((ext_vector_type(4)));

__device__ __forceinline__ ushort_t f2b(float x) {
    uint32_t u = __float_as_uint(x);
    uint32_t r = (u + 0x7FFFu + ((u >> 16) & 1u)) >> 16;
    return (ushort_t)r;
}
__device__ __forceinline__ float sigm(float x) {
    return 1.f / (1.f + __expf(-x));
}

// ---------------- setup kernels ----------------

__global__ void k_init(int* __restrict__ cnt) {
    int i = blockIdx.x * blockDim.x + threadIdx.x;
    if (i < NPH) cnt[i] = 0;
}

// G0[d][e][n] = sum_k embed[e,k]*Wih0[d,n,k] + bih[0,d,n] + bhh[0,d,n]
__global__ void k_g0(const float* __restrict__ embed, const float* __restrict__ Wih0,
                     const float* __restrict__ bih, const float* __restrict__ bhh,
                     float* __restrict__ G0, float* __restrict__ bias1) {
    int i = blockIdx.x * blockDim.x + threadIdx.x;
    if (i < 2 * NE * FH) {
        int d = i / (NE * FH);
        int rem = i % (NE * FH);
        int e = rem / FH;
        int n = rem % FH;
        const float* er = embed + (size_t)e * E;
        const float* wr = Wih0 + ((size_t)d * FH + n) * E;
        float s = 0.f;
        #pragma unroll 8
        for (int k = 0; k < E; ++k) s += er[k] * wr[k];
        G0[i] = s + bih[(size_t)d * FH + n] + bhh[(size_t)d * FH + n];
    }
    if (i < 2 * FH) bias1[i] = bih[2 * FH + i] + bhh[2 * FH + i];
}

__global__ void k_state(const float* __restrict__ h0, const float* __restrict__ c0,
                        float* __restrict__ cst, ushort_t* __restrict__ hb16) {
    int i = blockIdx.x * blockDim.x + threadIdx.x;
    if (i >= 4 * B * H) return;
    cst[i] = c0[i];
    int cell = i / (B * H);
    int rem  = i % (B * H);
    hb16[((size_t)(cell * 2 + 1)) * (B * H) + rem] = f2b(h0[i]);   // parity 1 = step -1
}

__global__ void k_len(const int* __restrict__ lens, float* __restrict__ out_len) {
    int i = threadIdx.x;
    if (i < B) out_len[i] = (float)lens[i];
}

// ---------------- persistent kernel ----------------
// Grid barrier: per-phase arrival counters (zeroed each launch by k_init).
__device__ __forceinline__ void gbar(int* cnt, int p) {
    __syncthreads();
    if (threadIdx.x == 0) {
        __threadfence();
        __hip_atomic_fetch_add(&cnt[p], 1, __ATOMIC_RELEASE, __HIP_MEMORY_SCOPE_AGENT);
        while (__hip_atomic_load(&cnt[p], __ATOMIC_ACQUIRE, __HIP_MEMORY_SCOPE_AGENT) < NBLK) {
            __builtin_amdgcn_s_sleep(1);
        }
    }
    __syncthreads();
}

// Phase p: L0 computes step t=p (p<T); L1 computes step s=p-1 (1<=p<=T);
// OUT computes logits t2=p-2 (p>=2). hb16: [cell][parity][B][H] bf16.
__global__ __launch_bounds__(512, 2) void k_persist(
    const float* __restrict__ Whh, const float* __restrict__ Wih1,
    const float* __restrict__ G0, const float* __restrict__ bias1,
    float* __restrict__ cst, ushort_t* __restrict__ hb16,
    const int* __restrict__ tok, const int* __restrict__ lens,
    const float* __restrict__ Wout, const float* __restrict__ bout,
    float* __restrict__ out, int* __restrict__ cnt)
{
    extern __shared__ char smem[];
    const int bid = blockIdx.x;
    const int tid = threadIdx.x;
    const int lane = tid & 63, wave = tid >> 6;
    const int lrow = lane & 15, kg = lane >> 4;
    const int row0 = wave * 32;
    const int BH = B * H;

    // ---- one-time: stage weights into LDS (f32 -> bf16, XOR-swizzled) ----
    if (bid < 64) {
        const int cell = bid >> 5, jt = bid & 31, j0 = jt * 16;
        const float* Wsrc = Whh + (size_t)cell * FH * H;
        for (int r = wave; r < 64; r += 8) {
            int grow = (r >> 4) * 512 + j0 + (r & 15);      // gate*512 + j
            const float* src = Wsrc + (size_t)grow * H;
            int sw = (r & 7) << 4;
            for (int c = lane; c < H; c += 64) {
                int byte = ((r * H + c) * 2) ^ sw;
                *(ushort_t*)(smem + byte) = f2b(src[c]);
            }
        }
    } else if (bid < 192) {
        const int q = bid - 64, cell = 2 + (q >> 6), jt = q & 63, j0 = jt * 8;
        const float* Wi = Wih1 + (size_t)(cell - 2) * FH * (2 * H);
        const float* Wh = Whh + (size_t)cell * FH * H;
        for (int r = wave; r < 32; r += 8) {
            int grow = (r >> 3) * 512 + j0 + (r & 7);       // gate*512 + j
            const float* si = Wi + (size_t)grow * (2 * H);
            const float* sh = Wh + (size_t)grow * H;
            int sw = (r & 7) << 4;
            for (int c = lane; c < 1536; c += 64) {
                float v = (c < 1024) ? si[c] : sh[c - 1024];
                int byte = ((r * 1536 + c) * 2) ^ sw;
                *(ushort_t*)(smem + byte) = f2b(v);
            }
        }
    } else {
        for (int r = wave; r < NC; r += 8) {                // Wout rows, pitch 2048B
            const float* src = Wout + (size_t)r * (2 * H);
            int sw = (r & 7) << 4;
            for (int c = lane; c < 2 * H; c += 64) {
                int byte = ((r * (2 * H) + c) * 2) ^ sw;
                *(ushort_t*)(smem + byte) = f2b(src[c]);
            }
        }
    }
    __syncthreads();

    // role constants
    const int sw16 = (lrow & 7) << 4;   // read-side swizzle (row = frag*16 + lrow; frag*16 ≡ 0 mod 8)

    for (int p = 0; p < NPH; ++p) {
        if (bid < 64) {
            // ---------------- layer 0 ----------------
            if (p < T) {
                const int cell = bid >> 5, jt = bid & 31, j0 = jt * 16;
                const int parR = (p + 1) & 1, parW = p & 1;
                const ushort_t* A = hb16 + (size_t)(cell * 2 + parR) * BH;
                const ushort_t* ar0 = A + (size_t)(row0 + lrow) * H + kg * 8;

                f32x4 acc[2][4];
                #pragma unroll
                for (int m = 0; m < 2; ++m)
                    #pragma unroll
                    for (int g = 0; g < 4; ++g) acc[m][g] = (f32x4){0.f, 0.f, 0.f, 0.f};

                for (int k = 0; k < H; k += 32) {
                    bf16x8 a0 = *(const bf16x8*)(ar0 + k);
                    bf16x8 a1 = *(const bf16x8*)(ar0 + (size_t)16 * H + k);
                    int cb = (kg * 16 + k * 2) ^ sw16;
                    #pragma unroll
                    for (int g = 0; g < 4; ++g) {
                        bf16x8 bb = *(const bf16x8*)(smem + (g * 16 + lrow) * 1024 + cb);
                        acc[0][g] = __builtin_amdgcn_mfma_f32_16x16x32_bf16(a0, bb, acc[0][g], 0, 0, 0);
                        acc[1][g] = __builtin_amdgcn_mfma_f32_16x16x32_bf16(a1, bb, acc[1][g], 0, 0, 0);
                    }
                }

                const int j = j0 + lrow;
                #pragma unroll
                for (int mf = 0; mf < 2; ++mf) {
                    #pragma unroll
                    for (int r = 0; r < 4; ++r) {
                        int bb = row0 + mf * 16 + kg * 4 + r;
                        int tk = tok[(size_t)bb * T + p];
                        const float* g0 = G0 + ((size_t)cell * NE + tk) * FH + j;
                        float gi = acc[mf][0][r] + g0[0];
                        float gf = acc[mf][1][r] + g0[512];
                        float gg = acc[mf][2][r] + g0[1024];
                        float go = acc[mf][3][r] + g0[1536];
                        float ii = sigm(gi), ff = sigm(gf), oo = sigm(go);
                        float tg = tanhf(gg);
                        size_t ci = ((size_t)cell * B + bb) * H + j;
                        float cn = ff * cst[ci] + ii * tg;
                        cst[ci] = cn;
                        float hn = oo * tanhf(cn);
                        hb16[((size_t)(cell * 2 + parW) * B + bb) * H + j] = f2b(hn);
                    }
                }
            }
        } else if (bid < 192) {
            // ---------------- layer 1 ----------------
            if (p >= 1 && p <= T) {
                const int q = bid - 64, cell = 2 + (q >> 6), jt = q & 63, j0 = jt * 8;
                const int parY  = (p + 1) & 1;
                const int parR2 = p & 1;
                const int parW  = (p + 1) & 1;
                const ushort_t* A0 = hb16 + (size_t)(0 * 2 + parY) * BH;
                const ushort_t* A1 = hb16 + (size_t)(1 * 2 + parY) * BH;
                const ushort_t* A2 = hb16 + (size_t)(cell * 2 + parR2) * BH;

                f32x4 acc[2][2];
                #pragma unroll
                for (int m = 0; m < 2; ++m)
                    #pragma unroll
                    for (int n = 0; n < 2; ++n) acc[m][n] = (f32x4){0.f, 0.f, 0.f, 0.f};

                auto chunk = [&](const ushort_t* A, int koffB) {
                    const ushort_t* ar0 = A + (size_t)(row0 + lrow) * H + kg * 8;
                    for (int k = 0; k < H; k += 32) {
                        bf16x8 a0 = *(const bf16x8*)(ar0 + k);
                        bf16x8 a1 = *(const bf16x8*)(ar0 + (size_t)16 * H + k);
                        int cb = (koffB + kg * 16 + k * 2) ^ sw16;
                        bf16x8 b0 = *(const bf16x8*)(smem + (0 * 16 + lrow) * 3072 + cb);
                        bf16x8 b1 = *(const bf16x8*)(smem + (16 + lrow) * 3072 + cb);
                        acc[0][0] = __builtin_amdgcn_mfma_f32_16x16x32_bf16(a0, b0, acc[0][0], 0, 0, 0);
                        acc[0][1] = __builtin_amdgcn_mfma_f32_16x16x32_bf16(a0, b1, acc[0][1], 0, 0, 0);
                        acc[1][0] = __builtin_amdgcn_mfma_f32_16x16x32_bf16(a1, b0, acc[1][0], 0, 0, 0);
                        acc[1][1] = __builtin_amdgcn_mfma_f32_16x16x32_bf16(a1, b1, acc[1][1], 0, 0, 0);
                    }
                };
                chunk(A0, 0);        // y0 fwd half (cell0 h)
                chunk(A1, 1024);     // y0 bwd half (cell1 h)
                chunk(A2, 2048);     // own recurrent h

                const float* b1p = bias1 + (size_t)(cell - 2) * FH;
                const int cc = lrow;
                const int jj = j0 + (cc & 7);
                const int mfS = cc >> 3;                    // low lanes: mf=0, high: mf=1
                #pragma unroll
                for (int r = 0; r < 4; ++r) {
                    float a00 = acc[0][0][r], a01 = acc[0][1][r];
                    float a10 = acc[1][0][r], a11 = acc[1][1][r];
                    float e00 = __shfl_xor(a00, 8);
                    float e01 = __shfl_xor(a01, 8);
                    float e10 = __shfl_xor(a10, 8);
                    float e11 = __shfl_xor(a11, 8);
                    float gi, gf, gg, go;
                    if (mfS == 0) { gi = a00; gf = e00; gg = a01; go = e01; }
                    else          { gi = e10; gf = a10; gg = e11; go = a11; }
                    gi += b1p[jj];
                    gf += b1p[512 + jj];
                    gg += b1p[1024 + jj];
                    go += b1p[1536 + jj];
                    int bb = row0 + mfS * 16 + kg * 4 + r;
                    float ii = sigm(gi), ff = sigm(gf), oo = sigm(go);
                    float tg = tanhf(gg);
                    size_t ci = ((size_t)cell * B + bb) * H + jj;
                    float cn = ff * cst[ci] + ii * tg;
                    cst[ci] = cn;
                    float hn = oo * tanhf(cn);
                    hb16[((size_t)(cell * 2 + parW) * B + bb) * H + jj] = f2b(hn);
                }
            }
        } else {
            // ---------------- logits ----------------
            if (p >= 2) {
                const int t2 = p - 2, parL = p & 1;
                const int b = (bid - 192) * 8 + wave;
                const int c = lane & 31, kh = lane >> 5;
                const ushort_t* y2 = hb16 + (size_t)((2 + kh) * 2 + parL) * BH + (size_t)b * H;
                float sum = 0.f;
                if (c < NC) {
                    int sw = (c & 7) << 4;
                    int rowbase = c * 2048;
                    for (int k = 0; k < H; k += 8) {
                        bf16x8 v = *(const bf16x8*)(y2 + k);
                        int cb = ((kh * 512 + k) * 2) ^ sw;
                        bf16x8 w = *(const bf16x8*)(smem + rowbase + cb);
                        #pragma unroll
                        for (int i = 0; i < 8; ++i) sum += (float)v[i] * (float)w[i];
                    }
                }
                sum += __shfl_xor(sum, 32);
                if (kh == 0 && c < NC) {
                    float val = sum + bout[c];
                    out[((size_t)b * T + t2) * NC + c] = (t2 < lens[b]) ? val : 0.f;
                }
            }
        }
        if (p < NPH - 1) gbar(cnt, p);
    }
}

// ---------------- launch ----------------

extern "C" void kernel_launch(void* const* d_in, const int* in_sizes, int n_in,
                              void* d_out, int out_size, void* d_ws, size_t ws_size,
                              hipStream_t stream) {
    const int*   tok   = (const int*)d_in[0];
    const int*   lens  = (const int*)d_in[1];
    const float* h0    = (const float*)d_in[2];
    const float* c0    = (const float*)d_in[3];
    const float* embed = (const float*)d_in[4];
    const float* Wih0  = (const float*)d_in[5];
    const float* Wih1  = (const float*)d_in[6];
    const float* Whh   = (const float*)d_in[7];
    const float* bih   = (const float*)d_in[8];
    const float* bhh   = (const float*)d_in[9];
    const float* Wout  = (const float*)d_in[10];
    const float* bout  = (const float*)d_in[11];
    float* out = (float*)d_out;

    // workspace layout
    ushort_t* hb16  = (ushort_t*)d_ws;                      // [4][2][B][H] bf16
    float*    fbase = (float*)(hb16 + (size_t)4 * 2 * B * H);
    float*    cst   = fbase;                                // [4][B][H] f32
    float*    G0    = cst + (size_t)4 * B * H;              // [2][28][2048] f32
    float*    bias1 = G0 + 2 * NE * FH;                     // [2][2048] f32
    int*      cnt   = (int*)(bias1 + 2 * FH);               // [NPH]

    (void)hipFuncSetAttribute((const void*)k_persist,
                              hipFuncAttributeMaxDynamicSharedMemorySize, LDS_BYTES);

    k_init<<<(NPH + 255) / 256, 256, 0, stream>>>(cnt);
    k_g0<<<(2 * NE * FH + 255) / 256, 256, 0, stream>>>(embed, Wih0, bih, bhh, G0, bias1);
    k_state<<<(4 * B * H + 255) / 256, 256, 0, stream>>>(h0, c0, cst, hb16);
    k_len<<<1, 256, 0, stream>>>(lens, out + (size_t)B * T * NC);

    k_persist<<<NBLK, 512, LDS_BYTES, stream>>>(Whh, Wih1, G0, bias1, cst, hb16,
                                                tok, lens, Wout, bout, out, cnt);
}